// Round 10
// baseline (452.129 us; speedup 1.0000x reference)
//
#include <hip/hip_runtime.h>

#define DD   121
#define NHID 15
#define NBLK 5
#define KS   11
#define IW   4096
#define OW   2043

// DPP row-rotate add: v += rotate_within_16_lane_row(v, N). VALU-only reduce.
#define ROR_ADD(v, N)                                                         \
  v += __int_as_float(__builtin_amdgcn_update_dpp(                            \
      0, __float_as_int(v), 0x120 + (N), 0xF, 0xF, true))

// Packed staging: W1 direct; W2 as per-idx (m,a) pairs; b2 as (m,a) pairs.
__device__ __forceinline__ void stage_weights(
    float* W1d, float* W2d, float* b2d, float* b1d,
    const float* __restrict__ W1, const float* __restrict__ W2,
    const float* __restrict__ b2, const float* __restrict__ b1,
    int blk, int t0, int nt)
{
    const float* W1b = W1 + blk * NHID * DD;
    const float* W2b = W2 + blk * 2 * DD * NHID;
    const float* b2b = b2 + blk * 2 * DD;
    for (int i = t0; i < NHID * DD; i += nt) W1d[i] = W1b[i];   // [j*DD+idx]
    for (int k = t0; k < DD * NHID; k += nt) {
        const int idx = k / NHID, j = k - idx * NHID;
        W2d[idx*32 + 2*j]     = W2b[idx*NHID + j];         // m-weight
        W2d[idx*32 + 2*j + 1] = W2b[(DD + idx)*NHID + j];  // loga-weight
    }
    for (int i = t0; i < DD; i += nt) {
        b2d[2*i]     = b2b[i];
        b2d[2*i + 1] = b2b[DD + i];
    }
    for (int i = t0; i < NHID; i += nt) b1d[i] = b1[blk*NHID + i];
}

// ---------------------------------------------------------------------------
// Flow inverse (MAF) + post-process. 2 waves: wave0 scans (lanes 0..15, DPP
// reduce, DEPTH-2 operand prefetch -> LDS latency hidden under 2 steps),
// wave1 stages next block's weights into the other LDS buffer.
// ---------------------------------------------------------------------------
__global__ __launch_bounds__(128) void flow_kernel(
    const float* __restrict__ kc,
    const float* __restrict__ W1, const float* __restrict__ b1,
    const float* __restrict__ W2, const float* __restrict__ b2,
    const float* __restrict__ lg, const float* __restrict__ beta,
    const float* __restrict__ mean, const float* __restrict__ var,
    float* __restrict__ kout)
{
    __shared__ float xs[DD];
    __shared__ float us[DD];
    __shared__ float W1s[2][NHID * DD];
    __shared__ float W2p[2][DD * 32];     // [idx*32 + 2j] = (m, a) pair
    __shared__ float b2p[2][DD * 2];      // [2*idx] = (m, a) pair
    __shared__ float b1s[2][16];

    const int tid  = threadIdx.x;
    const int wv   = tid >> 6;
    const int lane = tid & 63;

    stage_weights(W1s[0], W2p[0], b2p[0], b1s[0], W1, W2, b2, b1, NBLK - 1, tid, 128);
    if (tid < DD) xs[tid] = kc[tid];
    __syncthreads();

    for (int b = NBLK - 1; b >= 0; --b) {
        const int buf = (NBLK - 1 - b) & 1;
        if (wv == 1) {
            if (b > 0)
                stage_weights(W1s[buf^1], W2p[buf^1], b2p[buf^1], b1s[buf^1],
                              W1, W2, b2, b1, b - 1, lane, 64);
        } else {
            // BatchNorm inverse (eval): x = (x-beta)*exp(-lg)*sqrt(var+eps)+mean
            for (int i = lane; i < DD; i += 64) {
                float s = sqrtf(var[b*DD + i] + 1e-5f);
                us[i] = (xs[i] - beta[b*DD + i]) * __expf(-lg[b*DD + i]) * s + mean[b*DD + i];
            }
            const int evenb = ((b & 1) == 0);
            if (lane < 16) {
                const int j = lane;
                float pre_h = (j < NHID) ? b1s[buf][j] : 0.f;
                int i0 = evenb ? 0 : (DD - 1);
                int i1 = evenb ? 1 : (DD - 2);
                float2 wp0 = *(const float2*)&W2p[buf][i0*32 + 2*j];
                float  w10 = W1s[buf][j*DD + i0];
                float  uv0 = us[i0];
                float2 bp0 = *(const float2*)&b2p[buf][2*i0];
                float2 wp1 = *(const float2*)&W2p[buf][i1*32 + 2*j];
                float  w11 = W1s[buf][j*DD + i1];
                float  uv1 = us[i1];
                float2 bp1 = *(const float2*)&b2p[buf][2*i1];
                for (int t = 0; t < DD; ++t) {
                    const int t2 = (t + 2 < DD) ? (t + 2) : t;
                    const int i2 = evenb ? t2 : (DD - 1 - t2);
                    float2 wp2 = *(const float2*)&W2p[buf][i2*32 + 2*j];
                    float  w12 = W1s[buf][j*DD + i2];
                    float  uv2 = us[i2];
                    float2 bp2 = *(const float2*)&b2p[buf][2*i2];
                    // output mask: t > j
                    float h  = (j < t && j < NHID) ? fmaxf(pre_h, 0.f) : 0.f;
                    float pm = h * wp0.x;
                    float pa = h * wp0.y;
                    ROR_ADD(pm, 1); ROR_ADD(pa, 1);
                    ROR_ADD(pm, 2); ROR_ADD(pa, 2);
                    ROR_ADD(pm, 4); ROR_ADD(pa, 4);
                    ROR_ADD(pm, 8); ROR_ADD(pa, 8);
                    const float m  = pm + bp0.x;
                    const float la = pa + bp0.y;
                    const float xv = fmaf(uv0, __expf(la), m);
                    // hidden mask: j >= t
                    if (j >= t && j < NHID) pre_h = fmaf(xv, w10, pre_h);
                    if (j == 0) xs[i0] = xv;
                    i0 = i1;  wp0 = wp1; w10 = w11; uv0 = uv1; bp0 = bp1;
                    i1 = i2;  wp1 = wp2; w11 = w12; uv1 = uv2; bp1 = bp2;
                }
            }
        }
        __syncthreads();
    }

    // post-process: y = (sigmoid(x)-a)/(1-2a); k = y/sum(y)
    if (tid < 64) {
        const float A = 1e-6f;
        float y0, y1 = 0.f;
        {
            float v = xs[tid];
            y0 = (1.f / (1.f + __expf(-v)) - A) / (1.f - 2.f*A);
        }
        if (tid + 64 < DD) {
            float v = xs[tid + 64];
            y1 = (1.f / (1.f + __expf(-v)) - A) / (1.f - 2.f*A);
        }
        float s = y0 + y1;
        #pragma unroll
        for (int off = 32; off >= 1; off >>= 1) s += __shfl_xor(s, off, 64);
        kout[tid] = y0 / s;
        if (tid + 64 < DD) kout[tid + 64] = y1 / s;
    }
}

// ---------------------------------------------------------------------------
// 11x11 stride-2 valid conv. Tile 256 wide x 8 tall outputs, 256 threads.
// Wave w owns output rows {2w, 2w+1}; lane l owns ox = 4l..4l+3 -> every LDS
// read is wave-contiguous (64 lanes x 16B = contiguous 1KB: bank-balanced,
// zero conflicts). Thread strip = 2 rows: 13 input-row loads feed 8 outputs.
// Input tile 521x25 parity-split (stride-2 -> unit stride). LDS 52.8KB.
// Weights: uniform-index global reads -> scalar loads (SGPR).
// ---------------------------------------------------------------------------
#define CTY 25
#define CSE 264

__global__ __launch_bounds__(256) void conv_kernel(
    const float* __restrict__ in, const float* __restrict__ kf,
    float* __restrict__ out)
{
    __shared__ __align__(16) float E[CTY * CSE];
    __shared__ __align__(16) float O[CTY * CSE];

    const int tid = threadIdx.x;
    const int cch = blockIdx.z;
    const int ox0 = blockIdx.x * 256;
    const int oy0 = blockIdx.y * 8;
    const int gx0 = ox0 * 2;          // multiple of 512 -> 16B-aligned rows
    const int gy0 = oy0 * 2;

    const float* __restrict__ inc = in + (size_t)cch * IW * IW;

    // ---- stage 25 rows x 521 words, parity-split ----
    {
        const int l = tid & 31;
        for (int r = tid >> 5; r < CTY; r += 8) {
            const int gy = gy0 + r;
            const bool rowok = (gy < IW);
            const float* rowp = inc + (size_t)gy * IW + gx0;
            for (int c = l; c < 130; c += 32) {      // words 4c..4c+3
                float4 g = make_float4(0.f, 0.f, 0.f, 0.f);
                if (rowok) {
                    if (gx0 + 4*c + 3 < IW) {
                        g = *(const float4*)(rowp + 4*c);
                    } else {
                        float t0 = (gx0 + 4*c + 0 < IW) ? rowp[4*c + 0] : 0.f;
                        float t1 = (gx0 + 4*c + 1 < IW) ? rowp[4*c + 1] : 0.f;
                        float t2 = (gx0 + 4*c + 2 < IW) ? rowp[4*c + 2] : 0.f;
                        float t3 = (gx0 + 4*c + 3 < IW) ? rowp[4*c + 3] : 0.f;
                        g = make_float4(t0, t1, t2, t3);
                    }
                }
                *(float2*)&E[r*CSE + 2*c] = make_float2(g.x, g.z);
                *(float2*)&O[r*CSE + 2*c] = make_float2(g.y, g.w);
            }
            if (l == 0) {                             // word 520 (even)
                float v = 0.f;
                if (rowok && (gx0 + 520) < IW) v = rowp[520];
                E[r*CSE + 260] = v;
            }
        }
    }
    __syncthreads();

    const int w = tid >> 6;     // wave 0..3 -> output rows 2w, 2w+1
    const int l = tid & 63;     // lane -> ox strip 4l..4l+3

    float acc[2][4] = {{0.f,0.f,0.f,0.f},{0.f,0.f,0.f,0.f}};

    #pragma unroll
    for (int rw = 0; rw < 13; ++rw) {
        const int row = 4*w + rw;
        const float* Er = &E[row*CSE + 4*l];
        const float* Or = &O[row*CSE + 4*l];
        const float4 ea = *(const float4*)(Er);
        const float4 eb = *(const float4*)(Er + 4);
        const float4 ex = *(const float4*)(Er + 8);   // only .x used; b128 keeps bank-balance
        const float4 oa = *(const float4*)(Or);
        const float4 ob = *(const float4*)(Or + 4);
        const float ev[9] = {ea.x,ea.y,ea.z,ea.w,eb.x,eb.y,eb.z,eb.w,ex.x};
        const float ov[8] = {oa.x,oa.y,oa.z,oa.w,ob.x,ob.y,ob.z,ob.w};
        #pragma unroll
        for (int q = 0; q < 2; ++q) {
            const int ky = rw - 2*q;
            if (ky < 0 || ky > 10) continue;
            #pragma unroll
            for (int m = 0; m < 6; ++m) {
                const float we = kf[ky*KS + 2*m];     // uniform -> s_load/SGPR
                #pragma unroll
                for (int j = 0; j < 4; ++j)
                    acc[q][j] = fmaf(ev[m + j], we, acc[q][j]);
            }
            #pragma unroll
            for (int m = 0; m < 5; ++m) {
                const float wo = kf[ky*KS + 2*m + 1]; // uniform -> s_load/SGPR
                #pragma unroll
                for (int j = 0; j < 4; ++j)
                    acc[q][j] = fmaf(ov[m + j], wo, acc[q][j]);
            }
        }
    }

    const bool okx = (ox0 + 255) < OW;   // interior x-block: no per-j guard
    #pragma unroll
    for (int q = 0; q < 2; ++q) {
        const int oy = oy0 + 2*w + q;
        if (oy >= OW) continue;
        const size_t base = ((size_t)cch * OW + oy) * OW;
        if (okx) {
            #pragma unroll
            for (int j = 0; j < 4; ++j)
                out[base + ox0 + 4*l + j] = acc[q][j];
        } else {
            #pragma unroll
            for (int j = 0; j < 4; ++j) {
                const int ox = ox0 + 4*l + j;
                if (ox < OW) out[base + ox] = acc[q][j];
            }
        }
    }
}

extern "C" void kernel_launch(void* const* d_in, const int* in_sizes, int n_in,
                              void* d_out, int out_size, void* d_ws, size_t ws_size,
                              hipStream_t stream)
{
    const float* in   = (const float*)d_in[0];
    const float* kc   = (const float*)d_in[1];
    const float* W1   = (const float*)d_in[2];
    const float* b1   = (const float*)d_in[3];
    const float* W2   = (const float*)d_in[4];
    const float* b2   = (const float*)d_in[5];
    const float* lg   = (const float*)d_in[6];
    const float* beta = (const float*)d_in[7];
    const float* mean = (const float*)d_in[8];
    const float* var  = (const float*)d_in[9];

    float* out  = (float*)d_out;
    float* kout = out + (size_t)3 * OW * OW;   // out_k lives at the tail of d_out

    flow_kernel<<<dim3(1), dim3(128), 0, stream>>>(kc, W1, b1, W2, b2, lg, beta, mean, var, kout);

    dim3 grid((OW + 255) / 256, (OW + 7) / 8, 3);
    conv_kernel<<<grid, dim3(256), 0, stream>>>(in, kout, out);
}

// Round 11
// 232.038 us; speedup vs baseline: 1.9485x; 1.9485x over previous
//
#include <hip/hip_runtime.h>

#define DD   121
#define NHID 15
#define NBLK 5
#define KS   11
#define IW   4096
#define OW   2043

// DPP row-rotate add: v += rotate_within_16_lane_row(v, N). VALU-only reduce.
#define ROR_ADD(v, N)                                                         \
  v += __int_as_float(__builtin_amdgcn_update_dpp(                            \
      0, __float_as_int(v), 0x120 + (N), 0xF, 0xF, true))

// Packed staging: W1 direct; W2 as per-idx (m,a) pairs; b2 as (m,a) pairs.
__device__ __forceinline__ void stage_weights(
    float* W1d, float* W2d, float* b2d, float* b1d,
    const float* __restrict__ W1, const float* __restrict__ W2,
    const float* __restrict__ b2, const float* __restrict__ b1,
    int blk, int t0, int nt)
{
    const float* W1b = W1 + blk * NHID * DD;
    const float* W2b = W2 + blk * 2 * DD * NHID;
    const float* b2b = b2 + blk * 2 * DD;
    for (int i = t0; i < NHID * DD; i += nt) W1d[i] = W1b[i];   // [j*DD+idx]
    for (int k = t0; k < DD * NHID; k += nt) {
        const int idx = k / NHID, j = k - idx * NHID;
        W2d[idx*32 + 2*j]     = W2b[idx*NHID + j];         // m-weight
        W2d[idx*32 + 2*j + 1] = W2b[(DD + idx)*NHID + j];  // loga-weight
    }
    for (int i = t0; i < DD; i += nt) {
        W2d[i*32 + 30] = 0.f;                              // pad lane 15 (no NaN garbage)
        W2d[i*32 + 31] = 0.f;
        b2d[2*i]     = b2b[i];
        b2d[2*i + 1] = b2b[DD + i];
    }
    for (int i = t0; i < NHID; i += nt) b1d[i] = b1[blk*NHID + i];
}

// ---------------------------------------------------------------------------
// Flow inverse (MAF) + post-process. 2 waves: wave0 scans (lanes 0..15, DPP
// reduce, 4-slot named-register prefetch distance 4 -> LDS latency fully
// hidden), wave1 stages next block's weights into the other LDS buffer.
// ---------------------------------------------------------------------------
__global__ __launch_bounds__(128) void flow_kernel(
    const float* __restrict__ kc,
    const float* __restrict__ W1, const float* __restrict__ b1,
    const float* __restrict__ W2, const float* __restrict__ b2,
    const float* __restrict__ lg, const float* __restrict__ beta,
    const float* __restrict__ mean, const float* __restrict__ var,
    float* __restrict__ kout)
{
    __shared__ float xs[DD];
    __shared__ float us[DD];
    __shared__ float W1s[2][NHID * DD];
    __shared__ float W2p[2][DD * 32];     // [idx*32 + 2j] = (m, a) pair
    __shared__ float b2p[2][DD * 2];      // [2*idx] = (m, a) pair
    __shared__ float b1s[2][16];

    const int tid  = threadIdx.x;
    const int wv   = tid >> 6;
    const int lane = tid & 63;

    stage_weights(W1s[0], W2p[0], b2p[0], b1s[0], W1, W2, b2, b1, NBLK - 1, tid, 128);
    if (tid < DD) xs[tid] = kc[tid];
    __syncthreads();

    for (int b = NBLK - 1; b >= 0; --b) {
        const int buf = (NBLK - 1 - b) & 1;
        if (wv == 1) {
            if (b > 0)
                stage_weights(W1s[buf^1], W2p[buf^1], b2p[buf^1], b1s[buf^1],
                              W1, W2, b2, b1, b - 1, lane, 64);
        } else {
            // BatchNorm inverse (eval): x = (x-beta)*exp(-lg)*sqrt(var+eps)+mean
            for (int i = lane; i < DD; i += 64) {
                float s = sqrtf(var[b*DD + i] + 1e-5f);
                us[i] = (xs[i] - beta[b*DD + i]) * __expf(-lg[b*DD + i]) * s + mean[b*DD + i];
            }
            const int evenb = ((b & 1) == 0);
            if (lane < 16) {
                const int j  = lane;
                const int jc = (j < NHID) ? j : (NHID - 1);   // clamp W1 row addr
                float pre_h = (j < NHID) ? b1s[buf][j] : 0.f;

                auto step = [&](int t, int iS, float2 wpS, float w1S, float uvS, float2 bpS) {
                    float h  = (j < t && j < NHID) ? fmaxf(pre_h, 0.f) : 0.f;
                    float pm = h * wpS.x;
                    float pa = h * wpS.y;
                    ROR_ADD(pm, 1); ROR_ADD(pa, 1);
                    ROR_ADD(pm, 2); ROR_ADD(pa, 2);
                    ROR_ADD(pm, 4); ROR_ADD(pa, 4);
                    ROR_ADD(pm, 8); ROR_ADD(pa, 8);
                    const float xv = fmaf(uvS, __expf(pa + bpS.y), pm + bpS.x);
                    if (j >= t && j < NHID) pre_h = fmaf(xv, w1S, pre_h);
                    if (j == 0) xs[iS] = xv;
                };

                int iA, iB, iC, iD;
                float2 wpA, wpB, wpC, wpD, bpA, bpB, bpC, bpD;
                float  w1A, w1B, w1C, w1D, uvA, uvB, uvC, uvD;

                #define PRELOAD(S, T) { const int tt = (T);                                 \
                    i##S  = evenb ? tt : (DD - 1 - tt);                                     \
                    wp##S = *(const float2*)&W2p[buf][i##S*32 + 2*j];                       \
                    w1##S = W1s[buf][jc*DD + i##S];                                         \
                    uv##S = us[i##S];                                                       \
                    bp##S = *(const float2*)&b2p[buf][2*i##S]; }

                #define QSTEP(S, TCUR, TNEXT) {                                             \
                    int tt = (TNEXT); if (tt > DD - 1) tt = DD - 1;                         \
                    const int ip = evenb ? tt : (DD - 1 - tt);                              \
                    const float2 wpN = *(const float2*)&W2p[buf][ip*32 + 2*j];              \
                    const float  w1N = W1s[buf][jc*DD + ip];                                \
                    const float  uvN = us[ip];                                              \
                    const float2 bpN = *(const float2*)&b2p[buf][2*ip];                     \
                    step((TCUR), i##S, wp##S, w1##S, uv##S, bp##S);                         \
                    i##S = ip; wp##S = wpN; w1##S = w1N; uv##S = uvN; bp##S = bpN; }

                PRELOAD(A, 0) PRELOAD(B, 1) PRELOAD(C, 2) PRELOAD(D, 3)
                #pragma unroll 1
                for (int it = 0; it < 30; ++it) {        // t = 4it .. 4it+3; DD-1=120=4*30
                    QSTEP(A, 4*it + 0, 4*it + 4)
                    QSTEP(B, 4*it + 1, 4*it + 5)
                    QSTEP(C, 4*it + 2, 4*it + 6)
                    QSTEP(D, 4*it + 3, 4*it + 7)
                }
                step(DD - 1, iA, wpA, w1A, uvA, bpA);    // final step t=120
                #undef PRELOAD
                #undef QSTEP
            }
        }
        __syncthreads();
    }

    // post-process: y = (sigmoid(x)-a)/(1-2a); k = y/sum(y)
    if (tid < 64) {
        const float A = 1e-6f;
        float y0, y1 = 0.f;
        {
            float v = xs[tid];
            y0 = (1.f / (1.f + __expf(-v)) - A) / (1.f - 2.f*A);
        }
        if (tid + 64 < DD) {
            float v = xs[tid + 64];
            y1 = (1.f / (1.f + __expf(-v)) - A) / (1.f - 2.f*A);
        }
        float s = y0 + y1;
        #pragma unroll
        for (int off = 32; off >= 1; off >>= 1) s += __shfl_xor(s, off, 64);
        kout[tid] = y0 / s;
        if (tid + 64 < DD) kout[tid + 64] = y1 / s;
    }
}

// ---------------------------------------------------------------------------
// 11x11 stride-2 valid conv, same kernel for all 3 channels.
// 256 threads -> 64x16 output tile (each thread 4x1). Input tile 137x41 in
// LDS, parity-split (stride-2 -> unit stride). SE=80: within-wave ty-groups
// differ by 2 rows; 2*80=160 = 0 mod 32 -> all four 16-lane groups read at the
// SAME bank phase (r5's empirically-low-conflict condition; r9's SE=72 gave
// phases {0,8,16,24} and 47M conflict cycles). LDS 26.2KB -> 6 blocks/CU.
// Weights: uniform-index global reads -> scalar loads (SGPR).
// NO launch_bounds min-waves (forced cap caused catastrophic spills, r6/r7);
// NO full-tile unroll with big live sets (VGPR 220 killed occupancy, r10).
// ---------------------------------------------------------------------------
#define TIY 41
#define SE  80

__global__ __launch_bounds__(256) void conv_kernel(
    const float* __restrict__ in, const float* __restrict__ kf,
    float* __restrict__ out)
{
    __shared__ __align__(16) float E[TIY * SE];
    __shared__ __align__(16) float O[TIY * SE];

    const int tid = threadIdx.x;
    const int cch = blockIdx.z;
    const int ox0 = blockIdx.x * 64;
    const int oy0 = blockIdx.y * 16;
    const int gx0 = ox0 * 2;          // multiple of 128 -> 16B-aligned rows
    const int gy0 = oy0 * 2;

    const float* __restrict__ inc = in + (size_t)cch * IW * IW;
    {
        const int l  = tid & 31;
        const int c4 = l * 4;                      // cols 0..127 via float4
        for (int r = tid >> 5; r < TIY; r += 8) {
            const int gy = gy0 + r;
            const float* rowp = inc + (size_t)gy * IW + gx0;
            float4 g = make_float4(0.f, 0.f, 0.f, 0.f);
            if (gy < IW) g = *(const float4*)(rowp + c4);   // cols 0..127 in-bounds in x
            *(float2*)&E[r*SE + (c4 >> 1)] = make_float2(g.x, g.z);
            *(float2*)&O[r*SE + (c4 >> 1)] = make_float2(g.y, g.w);
            if (l < 9) {                           // tail cols 128..136 (guarded)
                const int ct = 128 + l;
                float v = 0.f;
                if (gy < IW && (gx0 + ct) < IW) v = rowp[ct];
                if (ct & 1) O[r*SE + (ct >> 1)] = v;
                else        E[r*SE + (ct >> 1)] = v;
            }
        }
    }
    __syncthreads();

    const int tx = tid & 15;
    const int ty = tid >> 4;

    float acc[4] = {0.f, 0.f, 0.f, 0.f};

    #pragma unroll
    for (int ky = 0; ky < 11; ++ky) {
        const int row = 2*ty + ky;
        const float4 ea = *(const float4*)&E[row*SE + 4*tx];
        const float4 eb = *(const float4*)&E[row*SE + 4*tx + 4];
        const float  ec =                  E[row*SE + 4*tx + 8];
        const float4 oa = *(const float4*)&O[row*SE + 4*tx];
        const float4 ob = *(const float4*)&O[row*SE + 4*tx + 4];
        const float ev[9] = {ea.x,ea.y,ea.z,ea.w,eb.x,eb.y,eb.z,eb.w,ec};
        const float ov[8] = {oa.x,oa.y,oa.z,oa.w,ob.x,ob.y,ob.z,ob.w};
        #pragma unroll
        for (int m = 0; m < 6; ++m) {
            const float we = kf[ky*KS + 2*m];     // uniform -> s_load/SGPR
            #pragma unroll
            for (int j = 0; j < 4; ++j)
                acc[j] = fmaf(ev[m + j], we, acc[j]);
        }
        #pragma unroll
        for (int m = 0; m < 5; ++m) {
            const float wo = kf[ky*KS + 2*m + 1]; // uniform -> s_load/SGPR
            #pragma unroll
            for (int j = 0; j < 4; ++j)
                acc[j] = fmaf(ov[m + j], wo, acc[j]);
        }
    }

    const int oy = oy0 + ty;
    if (oy < OW) {
        const size_t base = ((size_t)cch * OW + oy) * OW;
        if ((ox0 + 63) < OW) {
            #pragma unroll
            for (int j = 0; j < 4; ++j)
                out[base + ox0 + 4*tx + j] = acc[j];
        } else {
            #pragma unroll
            for (int j = 0; j < 4; ++j) {
                const int ox = ox0 + 4*tx + j;
                if (ox < OW) out[base + ox] = acc[j];
            }
        }
    }
}

extern "C" void kernel_launch(void* const* d_in, const int* in_sizes, int n_in,
                              void* d_out, int out_size, void* d_ws, size_t ws_size,
                              hipStream_t stream)
{
    const float* in   = (const float*)d_in[0];
    const float* kc   = (const float*)d_in[1];
    const float* W1   = (const float*)d_in[2];
    const float* b1   = (const float*)d_in[3];
    const float* W2   = (const float*)d_in[4];
    const float* b2   = (const float*)d_in[5];
    const float* lg   = (const float*)d_in[6];
    const float* beta = (const float*)d_in[7];
    const float* mean = (const float*)d_in[8];
    const float* var  = (const float*)d_in[9];

    float* out  = (float*)d_out;
    float* kout = out + (size_t)3 * OW * OW;   // out_k lives at the tail of d_out

    flow_kernel<<<dim3(1), dim3(128), 0, stream>>>(kc, W1, b1, W2, b2, lg, beta, mean, var, kout);

    dim3 grid((OW + 63) / 64, (OW + 15) / 16, 3);
    conv_kernel<<<grid, dim3(256), 0, stream>>>(in, kout, out);
}

// Round 12
// 218.149 us; speedup vs baseline: 2.0726x; 1.0637x over previous
//
#include <hip/hip_runtime.h>

#define DD   121
#define NHID 15
#define NBLK 5
#define KS   11
#define IW   4096
#define OW   2043

// DPP row-rotate add: v += rotate_within_16_lane_row(v, N). VALU-only reduce.
#define ROR_ADD(v, N)                                                         \
  v += __int_as_float(__builtin_amdgcn_update_dpp(                            \
      0, __float_as_int(v), 0x120 + (N), 0xF, 0xF, true))

// Packed staging: W1 direct; W2 as per-idx (m,a) pairs; b2 as (m,a) pairs.
__device__ __forceinline__ void stage_weights(
    float* W1d, float* W2d, float* b2d, float* b1d,
    const float* __restrict__ W1, const float* __restrict__ W2,
    const float* __restrict__ b2, const float* __restrict__ b1,
    int blk, int t0, int nt)
{
    const float* W1b = W1 + blk * NHID * DD;
    const float* W2b = W2 + blk * 2 * DD * NHID;
    const float* b2b = b2 + blk * 2 * DD;
    for (int i = t0; i < NHID * DD; i += nt) W1d[i] = W1b[i];   // [j*DD+idx]
    for (int k = t0; k < DD * NHID; k += nt) {
        const int idx = k / NHID, j = k - idx * NHID;
        W2d[idx*32 + 2*j]     = W2b[idx*NHID + j];         // m-weight
        W2d[idx*32 + 2*j + 1] = W2b[(DD + idx)*NHID + j];  // loga-weight
    }
    for (int i = t0; i < DD; i += nt) {
        W2d[i*32 + 30] = 0.f;                              // pad lane 15 (no NaN garbage)
        W2d[i*32 + 31] = 0.f;
        b2d[2*i]     = b2b[i];
        b2d[2*i + 1] = b2b[DD + i];
    }
    for (int i = t0; i < NHID; i += nt) b1d[i] = b1[blk*NHID + i];
}

// ---------------------------------------------------------------------------
// Flow inverse (MAF) + post-process. 2 waves: wave0 scans (lanes 0..15, DPP
// reduce, 4-slot named-register prefetch distance 4), wave1 stages next
// block's weights into the other LDS buffer. (unchanged from r11)
// ---------------------------------------------------------------------------
__global__ __launch_bounds__(128) void flow_kernel(
    const float* __restrict__ kc,
    const float* __restrict__ W1, const float* __restrict__ b1,
    const float* __restrict__ W2, const float* __restrict__ b2,
    const float* __restrict__ lg, const float* __restrict__ beta,
    const float* __restrict__ mean, const float* __restrict__ var,
    float* __restrict__ kout)
{
    __shared__ float xs[DD];
    __shared__ float us[DD];
    __shared__ float W1s[2][NHID * DD];
    __shared__ float W2p[2][DD * 32];     // [idx*32 + 2j] = (m, a) pair
    __shared__ float b2p[2][DD * 2];      // [2*idx] = (m, a) pair
    __shared__ float b1s[2][16];

    const int tid  = threadIdx.x;
    const int wv   = tid >> 6;
    const int lane = tid & 63;

    stage_weights(W1s[0], W2p[0], b2p[0], b1s[0], W1, W2, b2, b1, NBLK - 1, tid, 128);
    if (tid < DD) xs[tid] = kc[tid];
    __syncthreads();

    for (int b = NBLK - 1; b >= 0; --b) {
        const int buf = (NBLK - 1 - b) & 1;
        if (wv == 1) {
            if (b > 0)
                stage_weights(W1s[buf^1], W2p[buf^1], b2p[buf^1], b1s[buf^1],
                              W1, W2, b2, b1, b - 1, lane, 64);
        } else {
            // BatchNorm inverse (eval): x = (x-beta)*exp(-lg)*sqrt(var+eps)+mean
            for (int i = lane; i < DD; i += 64) {
                float s = sqrtf(var[b*DD + i] + 1e-5f);
                us[i] = (xs[i] - beta[b*DD + i]) * __expf(-lg[b*DD + i]) * s + mean[b*DD + i];
            }
            const int evenb = ((b & 1) == 0);
            if (lane < 16) {
                const int j  = lane;
                const int jc = (j < NHID) ? j : (NHID - 1);   // clamp W1 row addr
                float pre_h = (j < NHID) ? b1s[buf][j] : 0.f;

                auto step = [&](int t, int iS, float2 wpS, float w1S, float uvS, float2 bpS) {
                    float h  = (j < t && j < NHID) ? fmaxf(pre_h, 0.f) : 0.f;
                    float pm = h * wpS.x;
                    float pa = h * wpS.y;
                    ROR_ADD(pm, 1); ROR_ADD(pa, 1);
                    ROR_ADD(pm, 2); ROR_ADD(pa, 2);
                    ROR_ADD(pm, 4); ROR_ADD(pa, 4);
                    ROR_ADD(pm, 8); ROR_ADD(pa, 8);
                    const float xv = fmaf(uvS, __expf(pa + bpS.y), pm + bpS.x);
                    if (j >= t && j < NHID) pre_h = fmaf(xv, w1S, pre_h);
                    if (j == 0) xs[iS] = xv;
                };

                int iA, iB, iC, iD;
                float2 wpA, wpB, wpC, wpD, bpA, bpB, bpC, bpD;
                float  w1A, w1B, w1C, w1D, uvA, uvB, uvC, uvD;

                #define PRELOAD(S, T) { const int tt = (T);                                 \
                    i##S  = evenb ? tt : (DD - 1 - tt);                                     \
                    wp##S = *(const float2*)&W2p[buf][i##S*32 + 2*j];                       \
                    w1##S = W1s[buf][jc*DD + i##S];                                         \
                    uv##S = us[i##S];                                                       \
                    bp##S = *(const float2*)&b2p[buf][2*i##S]; }

                #define QSTEP(S, TCUR, TNEXT) {                                             \
                    int tt = (TNEXT); if (tt > DD - 1) tt = DD - 1;                         \
                    const int ip = evenb ? tt : (DD - 1 - tt);                              \
                    const float2 wpN = *(const float2*)&W2p[buf][ip*32 + 2*j];              \
                    const float  w1N = W1s[buf][jc*DD + ip];                                \
                    const float  uvN = us[ip];                                              \
                    const float2 bpN = *(const float2*)&b2p[buf][2*ip];                     \
                    step((TCUR), i##S, wp##S, w1##S, uv##S, bp##S);                         \
                    i##S = ip; wp##S = wpN; w1##S = w1N; uv##S = uvN; bp##S = bpN; }

                PRELOAD(A, 0) PRELOAD(B, 1) PRELOAD(C, 2) PRELOAD(D, 3)
                #pragma unroll 1
                for (int it = 0; it < 30; ++it) {        // t = 4it .. 4it+3; DD-1=120=4*30
                    QSTEP(A, 4*it + 0, 4*it + 4)
                    QSTEP(B, 4*it + 1, 4*it + 5)
                    QSTEP(C, 4*it + 2, 4*it + 6)
                    QSTEP(D, 4*it + 3, 4*it + 7)
                }
                step(DD - 1, iA, wpA, w1A, uvA, bpA);    // final step t=120
                #undef PRELOAD
                #undef QSTEP
            }
        }
        __syncthreads();
    }

    // post-process: y = (sigmoid(x)-a)/(1-2a); k = y/sum(y)
    if (tid < 64) {
        const float A = 1e-6f;
        float y0, y1 = 0.f;
        {
            float v = xs[tid];
            y0 = (1.f / (1.f + __expf(-v)) - A) / (1.f - 2.f*A);
        }
        if (tid + 64 < DD) {
            float v = xs[tid + 64];
            y1 = (1.f / (1.f + __expf(-v)) - A) / (1.f - 2.f*A);
        }
        float s = y0 + y1;
        #pragma unroll
        for (int off = 32; off >= 1; off >>= 1) s += __shfl_xor(s, off, 64);
        kout[tid] = y0 / s;
        if (tid + 64 < DD) kout[tid + 64] = y1 / s;
    }
}

// ---------------------------------------------------------------------------
// 11x11 stride-2 valid conv. Tile 256 wide x 8 tall outputs, 256 threads.
// Wave w owns output rows {2w, 2w+1}; lane l owns ox = 4l..4l+3 -> every LDS
// read instruction is WAVE-UNIFORM-ROW + lane-contiguous (64 x 16B = 1KB
// contiguous: bank-uniform, conflict-free; r10 evidence: 47M -> 24M).
// Row sharing: 13 input rows feed 8 outputs/lane (8.1 LDS reads/output vs
// r11's 13.75 -> attacks the LDS-pipe bound).
// #pragma unroll 1 on the row loop bounds the live set (r10's VGPR=220 bomb
// was full-unroll hoisting; r6/r7 showed forced launch_bounds also fatal).
// Weights: uniform-index global reads -> scalar loads (SGPR).
// ---------------------------------------------------------------------------
#define CTY 25
#define CSE 264

__global__ __launch_bounds__(256) void conv_kernel(
    const float* __restrict__ in, const float* __restrict__ kf,
    float* __restrict__ out)
{
    __shared__ __align__(16) float E[CTY * CSE];
    __shared__ __align__(16) float O[CTY * CSE];

    const int tid = threadIdx.x;
    const int cch = blockIdx.z;
    const int ox0 = blockIdx.x * 256;
    const int oy0 = blockIdx.y * 8;
    const int gx0 = ox0 * 2;          // multiple of 512 -> 16B-aligned rows
    const int gy0 = oy0 * 2;

    const float* __restrict__ inc = in + (size_t)cch * IW * IW;

    // ---- stage 25 rows x 521 words, parity-split ----
    {
        const int l = tid & 31;
        for (int r = tid >> 5; r < CTY; r += 8) {
            const int gy = gy0 + r;
            const bool rowok = (gy < IW);
            const float* rowp = inc + (size_t)gy * IW + gx0;
            for (int c = l; c < 130; c += 32) {      // words 4c..4c+3
                float4 g = make_float4(0.f, 0.f, 0.f, 0.f);
                if (rowok) {
                    if (gx0 + 4*c + 3 < IW) {
                        g = *(const float4*)(rowp + 4*c);
                    } else {
                        float t0 = (gx0 + 4*c + 0 < IW) ? rowp[4*c + 0] : 0.f;
                        float t1 = (gx0 + 4*c + 1 < IW) ? rowp[4*c + 1] : 0.f;
                        float t2 = (gx0 + 4*c + 2 < IW) ? rowp[4*c + 2] : 0.f;
                        float t3 = (gx0 + 4*c + 3 < IW) ? rowp[4*c + 3] : 0.f;
                        g = make_float4(t0, t1, t2, t3);
                    }
                }
                *(float2*)&E[r*CSE + 2*c] = make_float2(g.x, g.z);
                *(float2*)&O[r*CSE + 2*c] = make_float2(g.y, g.w);
            }
            if (l == 0) {                             // word 520 (even)
                float v = 0.f;
                if (rowok && (gx0 + 520) < IW) v = rowp[520];
                E[r*CSE + 260] = v;
            }
        }
    }
    __syncthreads();

    const int w = tid >> 6;     // wave 0..3 -> output rows 2w, 2w+1
    const int l = tid & 63;     // lane -> ox strip 4l..4l+3

    float acc[2][4] = {{0.f,0.f,0.f,0.f},{0.f,0.f,0.f,0.f}};

    #pragma unroll 1
    for (int rw = 0; rw < 13; ++rw) {
        const int row = 4*w + rw;
        const float* Er = &E[row*CSE + 4*l];
        const float* Or = &O[row*CSE + 4*l];
        const float4 ea = *(const float4*)(Er);
        const float4 eb = *(const float4*)(Er + 4);
        const float4 ex = *(const float4*)(Er + 8);   // only .x used; b128 keeps pattern uniform
        const float4 oa = *(const float4*)(Or);
        const float4 ob = *(const float4*)(Or + 4);
        const float ev[9] = {ea.x,ea.y,ea.z,ea.w,eb.x,eb.y,eb.z,eb.w,ex.x};
        const float ov[8] = {oa.x,oa.y,oa.z,oa.w,ob.x,ob.y,ob.z,ob.w};
        #pragma unroll
        for (int q = 0; q < 2; ++q) {
            const int ky = rw - 2*q;
            if (ky < 0 || ky > 10) continue;
            #pragma unroll
            for (int m = 0; m < 6; ++m) {
                const float we = kf[ky*KS + 2*m];     // uniform -> s_load/SGPR
                #pragma unroll
                for (int j = 0; j < 4; ++j)
                    acc[q][j] = fmaf(ev[m + j], we, acc[q][j]);
            }
            #pragma unroll
            for (int m = 0; m < 5; ++m) {
                const float wo = kf[ky*KS + 2*m + 1]; // uniform -> s_load/SGPR
                #pragma unroll
                for (int j = 0; j < 4; ++j)
                    acc[q][j] = fmaf(ov[m + j], wo, acc[q][j]);
            }
        }
    }

    const bool okx = (ox0 + 255) < OW;   // interior x-block: no per-j guard
    #pragma unroll
    for (int q = 0; q < 2; ++q) {
        const int oy = oy0 + 2*w + q;
        if (oy >= OW) continue;
        const size_t base = ((size_t)cch * OW + oy) * OW;
        if (okx) {
            #pragma unroll
            for (int j = 0; j < 4; ++j)
                out[base + ox0 + 4*l + j] = acc[q][j];
        } else {
            #pragma unroll
            for (int j = 0; j < 4; ++j) {
                const int ox = ox0 + 4*l + j;
                if (ox < OW) out[base + ox] = acc[q][j];
            }
        }
    }
}

extern "C" void kernel_launch(void* const* d_in, const int* in_sizes, int n_in,
                              void* d_out, int out_size, void* d_ws, size_t ws_size,
                              hipStream_t stream)
{
    const float* in   = (const float*)d_in[0];
    const float* kc   = (const float*)d_in[1];
    const float* W1   = (const float*)d_in[2];
    const float* b1   = (const float*)d_in[3];
    const float* W2   = (const float*)d_in[4];
    const float* b2   = (const float*)d_in[5];
    const float* lg   = (const float*)d_in[6];
    const float* beta = (const float*)d_in[7];
    const float* mean = (const float*)d_in[8];
    const float* var  = (const float*)d_in[9];

    float* out  = (float*)d_out;
    float* kout = out + (size_t)3 * OW * OW;   // out_k lives at the tail of d_out

    flow_kernel<<<dim3(1), dim3(128), 0, stream>>>(kc, W1, b1, W2, b2, lg, beta, mean, var, kout);

    dim3 grid((OW + 255) / 256, (OW + 7) / 8, 3);
    conv_kernel<<<grid, dim3(256), 0, stream>>>(in, kout, out);
}